// Round 9
// baseline (1533.063 us; speedup 1.0000x reference)
//
#include <hip/hip_runtime.h>
#include <hip/hip_bf16.h>

#define N_NODES 100000
#define N_EDGES 1600000
#define IN_DIM_ 256
#define HID_ 256
#define OUT_ 64
#define KSTEPS 10
#define NSLICE 4
#define NODEBLK 25000   // N_NODES/4 nodes per pass-grid

typedef __attribute__((ext_vector_type(4))) float f32x4;
typedef __attribute__((ext_vector_type(8))) __bf16 bf16x8;
typedef __attribute__((ext_vector_type(8))) unsigned short u16x8;

static __device__ __forceinline__ unsigned short f2bf(float f) {
    union { float f; unsigned int u; } v; v.f = f;
    unsigned int u = v.u;
    unsigned int r = u + 0x7FFFu + ((u >> 16) & 1u);  // RNE
    return (unsigned short)(r >> 16);
}
static __device__ __forceinline__ float bflo(unsigned int v) {
    return __uint_as_float(v << 16);
}
static __device__ __forceinline__ float bfhi(unsigned int v) {
    return __uint_as_float(v & 0xFFFF0000u);
}

// ---------------- small setup kernels ----------------

__global__ void gamma_kernel(const float* __restrict__ alpha, float* __restrict__ gamma) {
    if (threadIdx.x == 0) {
        float m = alpha[0];
        for (int i = 1; i <= KSTEPS; ++i) m = fmaxf(m, alpha[i]);
        float e[KSTEPS + 1];
        float s = 0.f;
        for (int i = 0; i <= KSTEPS; ++i) { e[i] = expf(alpha[i] - m); s += e[i]; }
        float inv = 1.f / s;
        for (int i = 0; i <= KSTEPS; ++i) gamma[i] = e[i] * inv;
    }
}

__global__ void deg_kernel(const int* __restrict__ row, int* __restrict__ deg, int E) {
    int e = blockIdx.x * 256 + threadIdx.x;
    if (e < E) atomicAdd(&deg[row[e]], 1);
}

__global__ void dis_kernel(const int* __restrict__ deg, float* __restrict__ dis, int n) {
    int i = blockIdx.x * 256 + threadIdx.x;
    if (i < n) {
        int d = deg[i];
        dis[i] = d > 0 ? rsqrtf((float)d) : 0.f;
    }
}

// transpose+cast weights once: wT[n][k] = bf16(W[k][n])
__global__ void wcast_kernel(const float* __restrict__ W, unsigned short* __restrict__ wT,
                             int K, int N) {
    int k = blockIdx.x * 256 + threadIdx.x;
    int n = blockIdx.y;
    if (k < K) wT[(size_t)n * K + k] = f2bf(W[(size_t)k * N + n]);
}

// ---------------- hierarchical scan ----------------

__global__ __launch_bounds__(256) void scan_sum_kernel(const int* __restrict__ deg,
                                                       int* __restrict__ bsum, int n) {
    __shared__ int s[256];
    int t = threadIdx.x;
    int i = blockIdx.x * 256 + t;
    s[t] = (i < n) ? deg[i] : 0;
    __syncthreads();
    for (int st = 128; st > 0; st >>= 1) {
        if (t < st) s[t] += s[t + st];
        __syncthreads();
    }
    if (t == 0) bsum[blockIdx.x] = s[0];
}

__global__ __launch_bounds__(512) void scan_block_kernel(int* __restrict__ bsum,
                                                         int* __restrict__ off,
                                                         int nblk, int n) {
    __shared__ int s[512];
    int t = threadIdx.x;
    int v = (t < nblk) ? bsum[t] : 0;
    s[t] = v;
    __syncthreads();
    for (int st = 1; st < 512; st <<= 1) {
        int a = (t >= st) ? s[t - st] : 0;
        __syncthreads();
        s[t] += a;
        __syncthreads();
    }
    if (t < nblk) bsum[t] = s[t] - v;  // exclusive
    if (t == 511) off[n] = s[511];     // total = E
}

__global__ __launch_bounds__(256) void scan_final_kernel(const int* __restrict__ deg,
                                                         const int* __restrict__ bsum,
                                                         int* __restrict__ off, int n) {
    __shared__ int s[256];
    int t = threadIdx.x;
    int i = blockIdx.x * 256 + t;
    int v = (i < n) ? deg[i] : 0;
    s[t] = v;
    __syncthreads();
    for (int st = 1; st < 256; st <<= 1) {
        int a = (t >= st) ? s[t - st] : 0;
        __syncthreads();
        s[t] += a;
        __syncthreads();
    }
    if (i < n) off[i] = bsum[blockIdx.x] + s[t] - v;
}

// R6 direct scatter (proven 87us), + R9 row-range sweep: per sweep the write
// window is ~12.5K nodes (~2MB of lines) -> fits per-XCD L2, lines fill before
// eviction. Per-node cursors keep atomic contention at ~deg (=16), unlike R8's
// per-bucket cursors (~1000-way, regressed).
__global__ void csr_scatter_kernel(const int* __restrict__ row, const int* __restrict__ col,
                                   const float* __restrict__ dis, const int* __restrict__ off,
                                   int* __restrict__ cursor, int2* __restrict__ ecsr, int E,
                                   int lo, int hi) {
    int e = blockIdx.x * 256 + threadIdx.x;
    if (e < E) {
        int r = row[e];
        if (r >= lo && r < hi) {
            int c = col[e];
            float w = dis[r] * dis[c];
            int pos = atomicAdd(&cursor[r], 1);
            int2 p;
            p.x = c;
            p.y = __float_as_int(w);
            ecsr[(size_t)off[r] + pos] = p;
        }
    }
}

// ---------------- MLP ----------------
// GEMM1 single-pass: block computes 64 rows x 256 cols. x fetched exactly once.
__global__ __launch_bounds__(256) void gemm1_kernel(const float* __restrict__ x,
                                                    const unsigned short* __restrict__ w1T,
                                                    const float* __restrict__ b1,
                                                    unsigned short* __restrict__ h1, int M) {
    __shared__ unsigned short As[64][40];
    __shared__ unsigned short Bs[256][40];

    const int tid = threadIdx.x;
    const int lane = tid & 63;
    const int w = tid >> 6;
    const int wr = w >> 1, wc = w & 1;          // wave tile: rows wr*32, cols wc*128
    const int row0 = blockIdx.x * 64;

    const int am = tid >> 2;
    const int ak = (tid & 3) * 8;

    f32x4 acc[2][8] = {};

    for (int kk = 0; kk < 256; kk += 32) {
        {
            int gr = row0 + am;
            u16x8 av;
            if (gr < M) {
                const float* p = x + (size_t)gr * IN_DIM_ + kk + ak;
                #pragma unroll
                for (int j = 0; j < 8; ++j) av[j] = f2bf(p[j]);
            } else {
                #pragma unroll
                for (int j = 0; j < 8; ++j) av[j] = 0;
            }
            *(u16x8*)&As[am][ak] = av;
        }
        {
            const unsigned short* p = w1T + (size_t)tid * 256 + kk;
            *(u16x8*)&Bs[tid][0]  = *(const u16x8*)&p[0];
            *(u16x8*)&Bs[tid][8]  = *(const u16x8*)&p[8];
            *(u16x8*)&Bs[tid][16] = *(const u16x8*)&p[16];
            *(u16x8*)&Bs[tid][24] = *(const u16x8*)&p[24];
        }
        __syncthreads();

        const int fr = lane & 15;
        const int ko = (lane >> 4) * 8;
        bf16x8 a[2];
        #pragma unroll
        for (int mi = 0; mi < 2; ++mi) a[mi] = *(const bf16x8*)&As[wr * 32 + mi * 16 + fr][ko];
        #pragma unroll
        for (int ni = 0; ni < 8; ++ni) {
            bf16x8 b = *(const bf16x8*)&Bs[wc * 128 + ni * 16 + fr][ko];
            #pragma unroll
            for (int mi = 0; mi < 2; ++mi)
                acc[mi][ni] = __builtin_amdgcn_mfma_f32_16x16x32_bf16(a[mi], b, acc[mi][ni], 0, 0, 0);
        }
        __syncthreads();
    }

    const int fr = lane & 15;
    const int rg = (lane >> 4) * 4;
    #pragma unroll
    for (int mi = 0; mi < 2; ++mi) {
        #pragma unroll
        for (int r = 0; r < 4; ++r) {
            int gm = row0 + wr * 32 + mi * 16 + rg + r;
            if (gm < M) {
                #pragma unroll
                for (int ni = 0; ni < 8; ++ni) {
                    int gn = wc * 128 + ni * 16 + fr;
                    float v = acc[mi][ni][r] + b1[gn];
                    v = fmaxf(v, 0.f);
                    h1[(size_t)gm * HID_ + gn] = f2bf(v);
                }
            }
        }
    }
}

// GEMM2 -> transposed slice layout: h_t[p][node][16] bf16, out_t[p][node][16] f32 = g0*v
__global__ __launch_bounds__(256) void gemm2_kernel(const unsigned short* __restrict__ h1,
                                                    const unsigned short* __restrict__ w2T,
                                                    const float* __restrict__ b2,
                                                    const float* __restrict__ gamma,
                                                    unsigned short* __restrict__ h_t,
                                                    float* __restrict__ out_t, int M) {
    __shared__ unsigned short As[64][40];
    __shared__ unsigned short Bs[64][40];

    const int tid = threadIdx.x;
    const int lane = tid & 63;
    const int w = tid >> 6;
    const int wr = w >> 1, wc = w & 1;
    const int row0 = blockIdx.x * 64;

    const int am = tid >> 2;
    const int ak = (tid & 3) * 8;

    f32x4 acc[2][2] = {};

    for (int kk = 0; kk < 256; kk += 32) {
        {
            int gr = row0 + am;
            if (gr < M) {
                *(u16x8*)&As[am][ak] = *(const u16x8*)&h1[(size_t)gr * HID_ + kk + ak];
            } else {
                u16x8 z = {};
                *(u16x8*)&As[am][ak] = z;
            }
        }
        if (tid < 128) {
            int n = tid >> 1, hf = (tid & 1) * 16;
            const unsigned short* p = &w2T[(size_t)n * 256 + kk + hf];
            *(u16x8*)&Bs[n][hf]     = *(const u16x8*)&p[0];
            *(u16x8*)&Bs[n][hf + 8] = *(const u16x8*)&p[8];
        }
        __syncthreads();

        const int fr = lane & 15;
        const int ko = (lane >> 4) * 8;
        bf16x8 a[2], b[2];
        #pragma unroll
        for (int mi = 0; mi < 2; ++mi) a[mi] = *(const bf16x8*)&As[wr * 32 + mi * 16 + fr][ko];
        #pragma unroll
        for (int ni = 0; ni < 2; ++ni) b[ni] = *(const bf16x8*)&Bs[wc * 32 + ni * 16 + fr][ko];
        #pragma unroll
        for (int mi = 0; mi < 2; ++mi)
            #pragma unroll
            for (int ni = 0; ni < 2; ++ni)
                acc[mi][ni] = __builtin_amdgcn_mfma_f32_16x16x32_bf16(a[mi], b[ni], acc[mi][ni], 0, 0, 0);
        __syncthreads();
    }

    const float g0 = gamma[0];
    const int fr = lane & 15;
    const int rg = (lane >> 4) * 4;
    #pragma unroll
    for (int mi = 0; mi < 2; ++mi) {
        #pragma unroll
        for (int r = 0; r < 4; ++r) {
            int gm = row0 + wr * 32 + mi * 16 + rg + r;
            if (gm < M) {
                #pragma unroll
                for (int ni = 0; ni < 2; ++ni) {
                    int gn = wc * 32 + ni * 16 + fr;
                    float v = acc[mi][ni][r] + b2[gn];
                    int p = gn >> 4, fo = gn & 15;
                    size_t o = (size_t)p * M * 16 + (size_t)gm * 16 + fo;
                    h_t[o] = f2bf(v);
                    out_t[o] = g0 * v;
                }
            }
        }
    }
}

// ---------------- propagation: sliced CSR pull ----------------
// Feature-independent propagation: 4 slices of 16 feats, hc slice = 3.2MB < 4MB
// per-XCD L2. blockIdx pass-major -> each XCD works one slice at a time
// (dispatch-order locality heuristic; correctness is order-independent).
// 8-lane group per edge, 8 edges/wave, shfl_xor(8/16/32) reduce.
__global__ __launch_bounds__(256) void pull_kernel(const int* __restrict__ off,
                                                   const int2* __restrict__ ecsr,
                                                   const unsigned short* __restrict__ hc_t,
                                                   unsigned short* __restrict__ hn_t,
                                                   float* __restrict__ out_t,
                                                   const float* __restrict__ gamma,
                                                   int k, int n) {
    int bid = blockIdx.x;
    int pass = bid / NODEBLK;
    int node = (bid % NODEBLK) * 4 + (threadIdx.x >> 6);
    if (node >= n) return;
    int lane = threadIdx.x & 63;
    int g = lane >> 3;        // edge group 0..7
    int fp = lane & 7;        // feature pair 0..7 within slice
    const unsigned short* hc = hc_t + (size_t)pass * n * 16;
    int s = off[node], e = off[node + 1];
    float a0 = 0.f, a1 = 0.f;

    int j = s + g;
    for (; j + 8 < e; j += 16) {  // 2 gathers in flight per lane
        int2 pA = ecsr[j];
        int2 pB = ecsr[j + 8];
        unsigned int vA = *(const unsigned int*)&hc[(size_t)pA.x * 16 + fp * 2];
        unsigned int vB = *(const unsigned int*)&hc[(size_t)pB.x * 16 + fp * 2];
        float wA = __int_as_float(pA.y), wB = __int_as_float(pB.y);
        a0 += wA * bflo(vA); a1 += wA * bfhi(vA);
        a0 += wB * bflo(vB); a1 += wB * bfhi(vB);
    }
    if (j < e) {
        int2 p = ecsr[j];
        unsigned int v = *(const unsigned int*)&hc[(size_t)p.x * 16 + fp * 2];
        float w = __int_as_float(p.y);
        a0 += w * bflo(v);
        a1 += w * bfhi(v);
    }

    a0 += __shfl_xor(a0, 8);  a1 += __shfl_xor(a1, 8);
    a0 += __shfl_xor(a0, 16); a1 += __shfl_xor(a1, 16);
    a0 += __shfl_xor(a0, 32); a1 += __shfl_xor(a1, 32);

    if (lane < 8) {
        float gk = gamma[k];
        size_t o = (size_t)pass * n * 16 + (size_t)node * 16 + fp * 2;
        unsigned int packed = (unsigned int)f2bf(a0) | ((unsigned int)f2bf(a1) << 16);
        *(unsigned int*)&hn_t[o] = packed;
        float2* op = (float2*)&out_t[o];
        float2 ov = *op;
        ov.x += gk * a0;
        ov.y += gk * a1;
        *op = ov;
    }
}

// out[n][64] <- out_t[4][n][16]
__global__ __launch_bounds__(256) void detrans_kernel(const float* __restrict__ out_t,
                                                      float* __restrict__ out, int n) {
    int i = blockIdx.x * 256 + threadIdx.x;  // one float4 per thread
    if (i < n * 16) {
        int node = i >> 4, f4 = i & 15;
        int p = f4 >> 2, q = f4 & 3;
        f32x4 v = *(const f32x4*)&out_t[(size_t)p * n * 16 + (size_t)node * 16 + q * 4];
        *(f32x4*)&out[(size_t)node * 64 + f4 * 4] = v;
    }
}

// ---------------- launcher ----------------
extern "C" void kernel_launch(void* const* d_in, const int* in_sizes, int n_in,
                              void* d_out, int out_size, void* d_ws, size_t ws_size,
                              hipStream_t stream) {
    const float* x = (const float*)d_in[0];
    const int* ei = (const int*)d_in[1];
    const float* W1 = (const float*)d_in[2];
    const float* b1 = (const float*)d_in[3];
    const float* W2 = (const float*)d_in[4];
    const float* b2 = (const float*)d_in[5];
    const float* alpha = (const float*)d_in[6];
    const int* row = ei;
    const int* col = ei + N_EDGES;
    float* out = (float*)d_out;

    const int NBLK = (N_NODES + 255) / 256;   // 391

    char* wsb = (char*)d_ws;
    size_t p = 0;
    auto alloc = [&](size_t bytes) { size_t r = p; p += (bytes + 255) & ~255ull; return r; };
    float* gamma = (float*)(wsb + alloc(16 * 4));
    int* off     = (int*)(wsb + alloc((N_NODES + 1) * 4));
    int* cursor  = (int*)(wsb + alloc(N_NODES * 4));
    int* deg     = (int*)(wsb + alloc(N_NODES * 4));
    float* dis   = (float*)(wsb + alloc(N_NODES * 4));
    int* bsum    = (int*)(wsb + alloc(512 * 4));
    unsigned short* w1T = (unsigned short*)(wsb + alloc((size_t)IN_DIM_ * HID_ * 2));
    unsigned short* w2T = (unsigned short*)(wsb + alloc((size_t)HID_ * OUT_ * 2));
    int2* ecsr   = (int2*)(wsb + alloc((size_t)N_EDGES * 8));
    float* out_t = (float*)(wsb + alloc((size_t)N_NODES * OUT_ * 4));               // 25.6MB
    unsigned short* h1  = (unsigned short*)(wsb + alloc((size_t)N_NODES * HID_ * 2)); // 51.2MB
    unsigned short* h_a = (unsigned short*)(wsb + alloc((size_t)N_NODES * OUT_ * 2)); // 12.8MB
    unsigned short* h_b = h1;  // h1 dead after gemm2

    hipMemsetAsync(cursor, 0, N_NODES * sizeof(int), stream);
    hipMemsetAsync(deg, 0, N_NODES * sizeof(int), stream);
    gamma_kernel<<<1, 64, 0, stream>>>(alpha, gamma);
    deg_kernel<<<(N_EDGES + 255) / 256, 256, 0, stream>>>(row, deg, N_EDGES);
    dis_kernel<<<NBLK, 256, 0, stream>>>(deg, dis, N_NODES);
    scan_sum_kernel<<<NBLK, 256, 0, stream>>>(deg, bsum, N_NODES);
    scan_block_kernel<<<1, 512, 0, stream>>>(bsum, off, NBLK, N_NODES);
    scan_final_kernel<<<NBLK, 256, 0, stream>>>(deg, bsum, off, N_NODES);
    for (int s = 0; s < 8; ++s) {
        csr_scatter_kernel<<<(N_EDGES + 255) / 256, 256, 0, stream>>>(
            row, col, dis, off, cursor, ecsr, N_EDGES, s * 12500, (s + 1) * 12500);
    }
    wcast_kernel<<<dim3(1, HID_), 256, 0, stream>>>(W1, w1T, IN_DIM_, HID_);
    wcast_kernel<<<dim3(1, OUT_), 256, 0, stream>>>(W2, w2T, HID_, OUT_);

    gemm1_kernel<<<(N_NODES + 63) / 64, 256, 0, stream>>>(x, w1T, b1, h1, N_NODES);
    gemm2_kernel<<<(N_NODES + 63) / 64, 256, 0, stream>>>(h1, w2T, b2, gamma, h_a, out_t,
                                                          N_NODES);

    unsigned short* hc = h_a;
    unsigned short* hn = h_b;
    for (int k = 1; k <= KSTEPS; ++k) {
        pull_kernel<<<NODEBLK * NSLICE, 256, 0, stream>>>(off, ecsr, hc, hn, out_t, gamma, k,
                                                          N_NODES);
        unsigned short* t = hc; hc = hn; hn = t;
    }
    detrans_kernel<<<(N_NODES * 16 + 255) / 256, 256, 0, stream>>>(out_t, out, N_NODES);
}

// Round 10
// 789.378 us; speedup vs baseline: 1.9421x; 1.9421x over previous
//
#include <hip/hip_runtime.h>
#include <hip/hip_bf16.h>

#define N_NODES 100000
#define N_EDGES 1600000
#define IN_DIM_ 256
#define HID_ 256
#define OUT_ 64
#define KSTEPS 10

typedef __attribute__((ext_vector_type(4))) float f32x4;
typedef __attribute__((ext_vector_type(8))) __bf16 bf16x8;
typedef __attribute__((ext_vector_type(8))) unsigned short u16x8;

static __device__ __forceinline__ unsigned short f2bf(float f) {
    union { float f; unsigned int u; } v; v.f = f;
    unsigned int u = v.u;
    unsigned int r = u + 0x7FFFu + ((u >> 16) & 1u);  // RNE
    return (unsigned short)(r >> 16);
}
static __device__ __forceinline__ float bflo(unsigned int v) {
    return __uint_as_float(v << 16);
}
static __device__ __forceinline__ float bfhi(unsigned int v) {
    return __uint_as_float(v & 0xFFFF0000u);
}

// ---------------- small setup kernels ----------------

__global__ void gamma_kernel(const float* __restrict__ alpha, float* __restrict__ gamma) {
    if (threadIdx.x == 0) {
        float m = alpha[0];
        for (int i = 1; i <= KSTEPS; ++i) m = fmaxf(m, alpha[i]);
        float e[KSTEPS + 1];
        float s = 0.f;
        for (int i = 0; i <= KSTEPS; ++i) { e[i] = expf(alpha[i] - m); s += e[i]; }
        float inv = 1.f / s;
        for (int i = 0; i <= KSTEPS; ++i) gamma[i] = e[i] * inv;
    }
}

__global__ void deg_kernel(const int* __restrict__ row, int* __restrict__ deg, int E) {
    int e = blockIdx.x * 256 + threadIdx.x;
    if (e < E) atomicAdd(&deg[row[e]], 1);
}

__global__ void dis_kernel(const int* __restrict__ deg, float* __restrict__ dis, int n) {
    int i = blockIdx.x * 256 + threadIdx.x;
    if (i < n) {
        int d = deg[i];
        dis[i] = d > 0 ? rsqrtf((float)d) : 0.f;
    }
}

// transpose+cast weights once: wT[n][k] = bf16(W[k][n])
__global__ void wcast_kernel(const float* __restrict__ W, unsigned short* __restrict__ wT,
                             int K, int N) {
    int k = blockIdx.x * 256 + threadIdx.x;
    int n = blockIdx.y;
    if (k < K) wT[(size_t)n * K + k] = f2bf(W[(size_t)k * N + n]);
}

// ---------------- hierarchical scan ----------------

__global__ __launch_bounds__(256) void scan_sum_kernel(const int* __restrict__ deg,
                                                       int* __restrict__ bsum, int n) {
    __shared__ int s[256];
    int t = threadIdx.x;
    int i = blockIdx.x * 256 + t;
    s[t] = (i < n) ? deg[i] : 0;
    __syncthreads();
    for (int st = 128; st > 0; st >>= 1) {
        if (t < st) s[t] += s[t + st];
        __syncthreads();
    }
    if (t == 0) bsum[blockIdx.x] = s[0];
}

__global__ __launch_bounds__(512) void scan_block_kernel(int* __restrict__ bsum,
                                                         int* __restrict__ off,
                                                         int nblk, int n) {
    __shared__ int s[512];
    int t = threadIdx.x;
    int v = (t < nblk) ? bsum[t] : 0;
    s[t] = v;
    __syncthreads();
    for (int st = 1; st < 512; st <<= 1) {
        int a = (t >= st) ? s[t - st] : 0;
        __syncthreads();
        s[t] += a;
        __syncthreads();
    }
    if (t < nblk) bsum[t] = s[t] - v;  // exclusive
    if (t == 511) off[n] = s[511];     // total = E
}

__global__ __launch_bounds__(256) void scan_final_kernel(const int* __restrict__ deg,
                                                         const int* __restrict__ bsum,
                                                         int* __restrict__ off, int n) {
    __shared__ int s[256];
    int t = threadIdx.x;
    int i = blockIdx.x * 256 + t;
    int v = (i < n) ? deg[i] : 0;
    s[t] = v;
    __syncthreads();
    for (int st = 1; st < 256; st <<= 1) {
        int a = (t >= st) ? s[t - st] : 0;
        __syncthreads();
        s[t] += a;
        __syncthreads();
    }
    if (i < n) off[i] = bsum[blockIdx.x] + s[t] - v;
}

// R6 direct scatter (proven 87us; R8 buckets and R9 sweeps both regressed)
__global__ void csr_scatter_kernel(const int* __restrict__ row, const int* __restrict__ col,
                                   const float* __restrict__ dis, const int* __restrict__ off,
                                   int* __restrict__ cursor, int2* __restrict__ ecsr, int E) {
    int e = blockIdx.x * 256 + threadIdx.x;
    if (e < E) {
        int r = row[e], c = col[e];
        float w = dis[r] * dis[c];
        int pos = atomicAdd(&cursor[r], 1);
        int2 p;
        p.x = c;
        p.y = __float_as_int(w);
        ecsr[(size_t)off[r] + pos] = p;
    }
}

// ---------------- MLP ----------------
// GEMM1 single-pass: block computes 64 rows x 256 cols. x fetched exactly once.
__global__ __launch_bounds__(256) void gemm1_kernel(const float* __restrict__ x,
                                                    const unsigned short* __restrict__ w1T,
                                                    const float* __restrict__ b1,
                                                    unsigned short* __restrict__ h1, int M) {
    __shared__ unsigned short As[64][40];
    __shared__ unsigned short Bs[256][40];

    const int tid = threadIdx.x;
    const int lane = tid & 63;
    const int w = tid >> 6;
    const int wr = w >> 1, wc = w & 1;          // wave tile: rows wr*32, cols wc*128
    const int row0 = blockIdx.x * 64;

    const int am = tid >> 2;
    const int ak = (tid & 3) * 8;

    f32x4 acc[2][8] = {};

    for (int kk = 0; kk < 256; kk += 32) {
        {
            int gr = row0 + am;
            u16x8 av;
            if (gr < M) {
                const float* p = x + (size_t)gr * IN_DIM_ + kk + ak;
                #pragma unroll
                for (int j = 0; j < 8; ++j) av[j] = f2bf(p[j]);
            } else {
                #pragma unroll
                for (int j = 0; j < 8; ++j) av[j] = 0;
            }
            *(u16x8*)&As[am][ak] = av;
        }
        {
            const unsigned short* p = w1T + (size_t)tid * 256 + kk;
            *(u16x8*)&Bs[tid][0]  = *(const u16x8*)&p[0];
            *(u16x8*)&Bs[tid][8]  = *(const u16x8*)&p[8];
            *(u16x8*)&Bs[tid][16] = *(const u16x8*)&p[16];
            *(u16x8*)&Bs[tid][24] = *(const u16x8*)&p[24];
        }
        __syncthreads();

        const int fr = lane & 15;
        const int ko = (lane >> 4) * 8;
        bf16x8 a[2];
        #pragma unroll
        for (int mi = 0; mi < 2; ++mi) a[mi] = *(const bf16x8*)&As[wr * 32 + mi * 16 + fr][ko];
        #pragma unroll
        for (int ni = 0; ni < 8; ++ni) {
            bf16x8 b = *(const bf16x8*)&Bs[wc * 128 + ni * 16 + fr][ko];
            #pragma unroll
            for (int mi = 0; mi < 2; ++mi)
                acc[mi][ni] = __builtin_amdgcn_mfma_f32_16x16x32_bf16(a[mi], b, acc[mi][ni], 0, 0, 0);
        }
        __syncthreads();
    }

    const int fr = lane & 15;
    const int rg = (lane >> 4) * 4;
    #pragma unroll
    for (int mi = 0; mi < 2; ++mi) {
        #pragma unroll
        for (int r = 0; r < 4; ++r) {
            int gm = row0 + wr * 32 + mi * 16 + rg + r;
            if (gm < M) {
                #pragma unroll
                for (int ni = 0; ni < 8; ++ni) {
                    int gn = wc * 128 + ni * 16 + fr;
                    float v = acc[mi][ni][r] + b1[gn];
                    v = fmaxf(v, 0.f);
                    h1[(size_t)gm * HID_ + gn] = f2bf(v);
                }
            }
        }
    }
}

// GEMM2: h = h1 @ W2 + b2 -> h bf16 [M,64]; out = gamma0*h (f32 pre-rounding)
__global__ __launch_bounds__(256) void gemm2_kernel(const unsigned short* __restrict__ h1,
                                                    const unsigned short* __restrict__ w2T,
                                                    const float* __restrict__ b2,
                                                    const float* __restrict__ gamma,
                                                    unsigned short* __restrict__ h,
                                                    float* __restrict__ out, int M) {
    __shared__ unsigned short As[64][40];
    __shared__ unsigned short Bs[64][40];

    const int tid = threadIdx.x;
    const int lane = tid & 63;
    const int w = tid >> 6;
    const int wr = w >> 1, wc = w & 1;
    const int row0 = blockIdx.x * 64;

    const int am = tid >> 2;
    const int ak = (tid & 3) * 8;

    f32x4 acc[2][2] = {};

    for (int kk = 0; kk < 256; kk += 32) {
        {
            int gr = row0 + am;
            if (gr < M) {
                *(u16x8*)&As[am][ak] = *(const u16x8*)&h1[(size_t)gr * HID_ + kk + ak];
            } else {
                u16x8 z = {};
                *(u16x8*)&As[am][ak] = z;
            }
        }
        if (tid < 128) {
            int n = tid >> 1, hf = (tid & 1) * 16;
            const unsigned short* p = &w2T[(size_t)n * 256 + kk + hf];
            *(u16x8*)&Bs[n][hf]     = *(const u16x8*)&p[0];
            *(u16x8*)&Bs[n][hf + 8] = *(const u16x8*)&p[8];
        }
        __syncthreads();

        const int fr = lane & 15;
        const int ko = (lane >> 4) * 8;
        bf16x8 a[2], b[2];
        #pragma unroll
        for (int mi = 0; mi < 2; ++mi) a[mi] = *(const bf16x8*)&As[wr * 32 + mi * 16 + fr][ko];
        #pragma unroll
        for (int ni = 0; ni < 2; ++ni) b[ni] = *(const bf16x8*)&Bs[wc * 32 + ni * 16 + fr][ko];
        #pragma unroll
        for (int mi = 0; mi < 2; ++mi)
            #pragma unroll
            for (int ni = 0; ni < 2; ++ni)
                acc[mi][ni] = __builtin_amdgcn_mfma_f32_16x16x32_bf16(a[mi], b[ni], acc[mi][ni], 0, 0, 0);
        __syncthreads();
    }

    const float g0 = gamma[0];
    const int fr = lane & 15;
    const int rg = (lane >> 4) * 4;
    #pragma unroll
    for (int mi = 0; mi < 2; ++mi) {
        #pragma unroll
        for (int r = 0; r < 4; ++r) {
            int gm = row0 + wr * 32 + mi * 16 + rg + r;
            if (gm < M) {
                #pragma unroll
                for (int ni = 0; ni < 2; ++ni) {
                    int gn = wc * 32 + ni * 16 + fr;
                    float v = acc[mi][ni][r] + b2[gn];
                    h[(size_t)gm * OUT_ + gn] = f2bf(v);
                    out[(size_t)gm * OUT_ + gn] = g0 * v;
                }
            }
        }
    }
}

// ---------------- propagation: R6 pull + window-2 axpy fusion (R10) ----------------
// out = sum_k gamma_k h_k carried as 51.2 MB RMW/step was the largest stream in
// the program (512 MB total). Even steps now fold BOTH gamma_{k-1} h_{k-1} (own
// row of hc, coalesced 12.8 MB read) and gamma_k h_k (in-register acc) into out;
// odd steps never touch out. 10 RMW passes -> 5, net -192 MB.
__global__ __launch_bounds__(256) void pull_kernel(const int* __restrict__ off,
                                                   const int2* __restrict__ ecsr,
                                                   const unsigned short* __restrict__ hc,
                                                   unsigned short* __restrict__ hn,
                                                   float* __restrict__ out,
                                                   const float* __restrict__ gamma,
                                                   int k, int fuse, int n) {
    int node = blockIdx.x * 4 + (threadIdx.x >> 6);
    if (node >= n) return;
    int lane = threadIdx.x & 63;
    int half = lane >> 5;
    int fl = (lane & 31) * 2;
    int s = off[node], e = off[node + 1];
    float acc0 = 0.f, acc1 = 0.f;

    int j = s + half;
    // 8 edges per half per iteration -> 8 outstanding gathers per lane
    for (; j + 14 < e; j += 16) {
        int2 p0 = ecsr[j],      p1 = ecsr[j + 2],  p2 = ecsr[j + 4],  p3 = ecsr[j + 6];
        int2 p4 = ecsr[j + 8],  p5 = ecsr[j + 10], p6 = ecsr[j + 12], p7 = ecsr[j + 14];
        unsigned int v0 = *(const unsigned int*)&hc[(size_t)p0.x * OUT_ + fl];
        unsigned int v1 = *(const unsigned int*)&hc[(size_t)p1.x * OUT_ + fl];
        unsigned int v2 = *(const unsigned int*)&hc[(size_t)p2.x * OUT_ + fl];
        unsigned int v3 = *(const unsigned int*)&hc[(size_t)p3.x * OUT_ + fl];
        unsigned int v4 = *(const unsigned int*)&hc[(size_t)p4.x * OUT_ + fl];
        unsigned int v5 = *(const unsigned int*)&hc[(size_t)p5.x * OUT_ + fl];
        unsigned int v6 = *(const unsigned int*)&hc[(size_t)p6.x * OUT_ + fl];
        unsigned int v7 = *(const unsigned int*)&hc[(size_t)p7.x * OUT_ + fl];
        float w0 = __int_as_float(p0.y), w1 = __int_as_float(p1.y);
        float w2 = __int_as_float(p2.y), w3 = __int_as_float(p3.y);
        float w4 = __int_as_float(p4.y), w5 = __int_as_float(p5.y);
        float w6 = __int_as_float(p6.y), w7 = __int_as_float(p7.y);
        acc0 += w0 * bflo(v0); acc1 += w0 * bfhi(v0);
        acc0 += w1 * bflo(v1); acc1 += w1 * bfhi(v1);
        acc0 += w2 * bflo(v2); acc1 += w2 * bfhi(v2);
        acc0 += w3 * bflo(v3); acc1 += w3 * bfhi(v3);
        acc0 += w4 * bflo(v4); acc1 += w4 * bfhi(v4);
        acc0 += w5 * bflo(v5); acc1 += w5 * bfhi(v5);
        acc0 += w6 * bflo(v6); acc1 += w6 * bfhi(v6);
        acc0 += w7 * bflo(v7); acc1 += w7 * bfhi(v7);
    }
    for (; j + 2 < e; j += 4) {
        int2 pa = ecsr[j], pb = ecsr[j + 2];
        unsigned int va = *(const unsigned int*)&hc[(size_t)pa.x * OUT_ + fl];
        unsigned int vb = *(const unsigned int*)&hc[(size_t)pb.x * OUT_ + fl];
        float wa = __int_as_float(pa.y), wb = __int_as_float(pb.y);
        acc0 += wa * bflo(va); acc1 += wa * bfhi(va);
        acc0 += wb * bflo(vb); acc1 += wb * bfhi(vb);
    }
    if (j < e) {
        int2 p = ecsr[j];
        unsigned int v = *(const unsigned int*)&hc[(size_t)p.x * OUT_ + fl];
        float w = __int_as_float(p.y);
        acc0 += w * bflo(v);
        acc1 += w * bfhi(v);
    }

    acc0 += __shfl_xor(acc0, 32);
    acc1 += __shfl_xor(acc1, 32);

    if (lane < 32) {
        size_t o = (size_t)node * OUT_ + fl;
        unsigned int packed = (unsigned int)f2bf(acc0) | ((unsigned int)f2bf(acc1) << 16);
        *(unsigned int*)&hn[o] = packed;
        if (fuse) {
            float gp = gamma[k - 1], gc = gamma[k];
            unsigned int hown = *(const unsigned int*)&hc[o];  // own row h_{k-1}[node]
            float2* op = (float2*)&out[o];
            float2 ov = *op;
            ov.x += gp * bflo(hown) + gc * acc0;
            ov.y += gp * bfhi(hown) + gc * acc1;
            *op = ov;
        }
    }
}

// ---------------- launcher ----------------
extern "C" void kernel_launch(void* const* d_in, const int* in_sizes, int n_in,
                              void* d_out, int out_size, void* d_ws, size_t ws_size,
                              hipStream_t stream) {
    const float* x = (const float*)d_in[0];
    const int* ei = (const int*)d_in[1];
    const float* W1 = (const float*)d_in[2];
    const float* b1 = (const float*)d_in[3];
    const float* W2 = (const float*)d_in[4];
    const float* b2 = (const float*)d_in[5];
    const float* alpha = (const float*)d_in[6];
    const int* row = ei;
    const int* col = ei + N_EDGES;
    float* out = (float*)d_out;

    const int NBLK = (N_NODES + 255) / 256;   // 391

    char* wsb = (char*)d_ws;
    size_t p = 0;
    auto alloc = [&](size_t bytes) { size_t r = p; p += (bytes + 255) & ~255ull; return r; };
    float* gamma = (float*)(wsb + alloc(16 * 4));
    int* off     = (int*)(wsb + alloc((N_NODES + 1) * 4));
    int* cursor  = (int*)(wsb + alloc(N_NODES * 4));
    int* deg     = (int*)(wsb + alloc(N_NODES * 4));
    float* dis   = (float*)(wsb + alloc(N_NODES * 4));
    int* bsum    = (int*)(wsb + alloc(512 * 4));
    unsigned short* w1T = (unsigned short*)(wsb + alloc((size_t)IN_DIM_ * HID_ * 2));
    unsigned short* w2T = (unsigned short*)(wsb + alloc((size_t)HID_ * OUT_ * 2));
    int2* ecsr   = (int2*)(wsb + alloc((size_t)N_EDGES * 8));
    unsigned short* h1  = (unsigned short*)(wsb + alloc((size_t)N_NODES * HID_ * 2)); // 51.2MB
    unsigned short* h_a = (unsigned short*)(wsb + alloc((size_t)N_NODES * OUT_ * 2)); // 12.8MB
    unsigned short* h_b = h1;  // h1 dead after gemm2

    hipMemsetAsync(cursor, 0, N_NODES * sizeof(int), stream);
    hipMemsetAsync(deg, 0, N_NODES * sizeof(int), stream);
    gamma_kernel<<<1, 64, 0, stream>>>(alpha, gamma);
    deg_kernel<<<(N_EDGES + 255) / 256, 256, 0, stream>>>(row, deg, N_EDGES);
    dis_kernel<<<NBLK, 256, 0, stream>>>(deg, dis, N_NODES);
    scan_sum_kernel<<<NBLK, 256, 0, stream>>>(deg, bsum, N_NODES);
    scan_block_kernel<<<1, 512, 0, stream>>>(bsum, off, NBLK, N_NODES);
    scan_final_kernel<<<NBLK, 256, 0, stream>>>(deg, bsum, off, N_NODES);
    csr_scatter_kernel<<<(N_EDGES + 255) / 256, 256, 0, stream>>>(row, col, dis, off, cursor,
                                                                  ecsr, N_EDGES);
    wcast_kernel<<<dim3(1, HID_), 256, 0, stream>>>(W1, w1T, IN_DIM_, HID_);
    wcast_kernel<<<dim3(1, OUT_), 256, 0, stream>>>(W2, w2T, HID_, OUT_);

    gemm1_kernel<<<(N_NODES + 63) / 64, 256, 0, stream>>>(x, w1T, b1, h1, N_NODES);
    gemm2_kernel<<<(N_NODES + 63) / 64, 256, 0, stream>>>(h1, w2T, b2, gamma, h_a, out, N_NODES);

    unsigned short* hc = h_a;
    unsigned short* hn = h_b;
    for (int k = 1; k <= KSTEPS; ++k) {
        int fuse = (k % 2 == 0);  // even steps fold gamma_{k-1} and gamma_k into out
        pull_kernel<<<(N_NODES + 3) / 4, 256, 0, stream>>>(off, ecsr, hc, hn, out, gamma, k,
                                                           fuse, N_NODES);
        unsigned short* t = hc; hc = hn; hn = t;
    }
}